// Round 1
// 1577.465 us; speedup vs baseline: 1.5004x; 1.5004x over previous
//
#include <hip/hip_runtime.h>
#include <cstdint>

// binary_disordered_RNNwavefunction: 128-step 2-layer GRU + MLP + softmax +
// threefry categorical sampling, B=8192, H=128, I=2.
//
// R7 (vs R6, 2366 us; MfmaUtil 18.8, VALUBusy 45.8, 1 block/CU):
//  1. HW transcendentals in combine phases: sigmoid/tanh via v_exp_f32+v_rcp,
//     cos via v_cos (|h2|<=1, no range reduction). 2-3 ulp ~= libm.
//  2. OUT(n-1) folded into merged-GEMM(n) phase: OUT reads S1 cols 384..511,
//     merged writes S0 + S1 cols 0..383 (disjoint). Hides the serial sampler
//     under the L2-BW-bound GEMM streaming; barriers 6 -> 5 per step.
//  3. Threefry key schedule (depends only on n) precomputed into LDS skey[128]
//     at init (bit-exact); u0/u1 counter calls split across ln==0/ln==1,
//     z compare via shfl_xor (identical float ops -> bit-exact sampling).
//  4. Cross-barrier B prefetch: GH1b tile0 issued at C0 start, W1 + next-step
//     merged tile0 at C1 start; biases prefetched at phase tops.
//
// Numerics (verified R4/R5, absmax 0.0039 = comparison floor): split-f16
// a = a1 + a2s/4096; 3 MFMAs/tile. RNG: modern JAX threefry semantics,
// float sampling path (expf/logf) kept bit-identical to R6.
// R2 lesson: few blocks, lockstep L2 reuse. R5 lesson: AI per B-load ~ BTM.

namespace {

constexpr int NSTEPS = 128;
constexpr int HDIM = 128;
constexpr int G3H = 384;

constexpr int BTM = 32;        // batch rows per block
constexpr int THM = 512;       // threads (8 waves)
constexpr int S0P = 385;       // S0 stride (==1 mod 32)
constexpr int S1P = 513;       // S1 stride (==1 mod 32)

// fallback (R3) config
constexpr int BT = 16;
constexpr int THREADS = 256;
constexpr int HP = 132;
constexpr int SP = 516;

typedef _Float16 half8 __attribute__((ext_vector_type(8)));
typedef float f32x4 __attribute__((ext_vector_type(4)));

constexpr float LO_SCALE = 4096.0f;
constexpr float LO_INV = 2.44140625e-4f;   // 1/4096
constexpr float F16_MIN_NORM = 6.104e-5f;
constexpr float LOG2E = 1.4426950408889634f;
constexpr float INV2PI = 0.15915494309189535f;

__device__ __forceinline__ void split_f16(float x, _Float16& a1, _Float16& a2s) {
  _Float16 h = (fabsf(x) < F16_MIN_NORM) ? (_Float16)0.0f : (_Float16)x;
  a1 = h;
  a2s = (_Float16)((x - (float)h) * LO_SCALE);
}

__device__ __forceinline__ void tf2x32(uint32_t k0, uint32_t k1,
                                       uint32_t x0, uint32_t x1,
                                       uint32_t& o0, uint32_t& o1) {
  const uint32_t ks2 = k0 ^ k1 ^ 0x1BD11BDAu;
  uint32_t v0 = x0 + k0;
  uint32_t v1 = x1 + k1;
  const uint32_t ks[3] = {k0, k1, ks2};
  const uint32_t rotA[4] = {13u, 15u, 26u, 6u};
  const uint32_t rotB[4] = {17u, 29u, 16u, 24u};
#pragma unroll
  for (int i = 0; i < 5; ++i) {
#pragma unroll
    for (int j = 0; j < 4; ++j) {
      const uint32_t r = (i & 1) ? rotB[j] : rotA[j];
      v0 += v1;
      v1 = (v1 << r) | (v1 >> (32u - r));
      v1 ^= v0;
    }
    v0 += ks[(i + 1) % 3];
    v1 += ks[(i + 2) % 3] + (uint32_t)(i + 1);
  }
  o0 = v0;
  o1 = v1;
}

__device__ __forceinline__ float u01_from_bits(uint32_t bits) {
  const float tiny = 1.1754943508222875e-38f;
  float f = __uint_as_float((bits >> 9) | 0x3F800000u) - 1.0f;
  float u = f * (1.0f - tiny) + tiny;
  return fmaxf(tiny, u);
}

// fast HW transcendentals (v_exp_f32 / v_rcp_f32 / v_cos_f32, ~1 ulp each)
__device__ __forceinline__ float fexp2(float x) { return __builtin_amdgcn_exp2f(x); }
__device__ __forceinline__ float frcp(float x) { return __builtin_amdgcn_rcpf(x); }
__device__ __forceinline__ float sigmoidf(float x) {
  return frcp(1.0f + fexp2(-LOG2E * x));
}
__device__ __forceinline__ float ftanhf(float x) {
  // tanh(x) = 1 - 2/(e^{2x}+1); exp2 over/underflow -> +-1 exactly
  return 1.0f - 2.0f * frcp(1.0f + fexp2((2.0f * LOG2E) * x));
}
__device__ __forceinline__ float fcosx(float x) {   // cos(x), |x| <= 1 rad
  return __builtin_amdgcn_cosf(x * INV2PI);
}

__device__ __forceinline__ float dot4(const float4 a, const float4 b, float c) {
  c = fmaf(a.x, b.x, c);
  c = fmaf(a.y, b.y, c);
  c = fmaf(a.z, b.z, c);
  c = fmaf(a.w, b.w, c);
  return c;
}

__device__ __forceinline__ void load_Afrag(const _Float16* arr, int lane,
                                           half8 (&A)[2][4]) {
#pragma unroll
  for (int mt = 0; mt < 2; ++mt)
#pragma unroll
    for (int kt = 0; kt < 4; ++kt)
      A[mt][kt] = *(const half8*)(arr + mt * 2048 + (kt * 64 + lane) * 8);
}

__device__ __forceinline__ void load_B(const _Float16* __restrict__ B1,
                                       const _Float16* __restrict__ B2,
                                       int jt, int lane,
                                       half8 (&b1)[4], half8 (&b2)[4]) {
#pragma unroll
  for (int kt = 0; kt < 4; ++kt) {
    const size_t o = ((size_t)(jt * 4 + kt) * 64 + lane) * 8;
    b1[kt] = *(const half8*)(B1 + o);
    b2[kt] = *(const half8*)(B2 + o);
  }
}

__device__ __forceinline__ void mfma_regs(const half8 (&A1)[2][4],
                                          const half8 (&A2)[2][4],
                                          const half8 (&b1)[4],
                                          const half8 (&b2)[4],
                                          f32x4 (&c1)[2], f32x4 (&c2)[2]) {
#pragma unroll
  for (int kt = 0; kt < 4; ++kt)
#pragma unroll
    for (int mt = 0; mt < 2; ++mt) {
      c1[mt] = __builtin_amdgcn_mfma_f32_16x16x32_f16(A1[mt][kt], b1[kt], c1[mt], 0, 0, 0);
      c2[mt] = __builtin_amdgcn_mfma_f32_16x16x32_f16(A1[mt][kt], b2[kt], c2[mt], 0, 0, 0);
      c2[mt] = __builtin_amdgcn_mfma_f32_16x16x32_f16(A2[mt][kt], b1[kt], c2[mt], 0, 0, 0);
    }
}

}  // namespace

// ---------------------------------------------------------------------------
// Preprocess: fp32 W[n][JT*16][128] -> frag-layout split-f16 arrays (as R4)
// ---------------------------------------------------------------------------
extern "C" __global__ __launch_bounds__(256)
void preprocess_split_kernel(const float* __restrict__ src,
                             _Float16* __restrict__ d1,
                             _Float16* __restrict__ d2,
                             int total, int JT) {
  const int idx = blockIdx.x * 256 + threadIdx.x;
  if (idx >= total) return;
  const int lane = idx & 63;
  const int kt = (idx >> 6) & 3;
  const int rest = idx >> 8;
  const int jt = rest % JT;
  const int nstep = rest / JT;

  const int j = jt * 16 + (lane & 15);
  const int k0 = kt * 32 + ((lane >> 4) << 3);
  const float* p = src + ((size_t)nstep * (JT * 16) + j) * 128 + k0;
  const float4 w0 = *(const float4*)p;
  const float4 w1 = *(const float4*)(p + 4);
  const float xs[8] = {w0.x, w0.y, w0.z, w0.w, w1.x, w1.y, w1.z, w1.w};

  half8 o1, o2;
#pragma unroll
  for (int t = 0; t < 8; ++t) {
    _Float16 a1, a2s;
    split_f16(xs[t], a1, a2s);
    o1[t] = a1;
    o2[t] = a2s;
  }
  *(half8*)(d1 + (size_t)idx * 8) = o1;
  *(half8*)(d2 + (size_t)idx * 8) = o2;
}

// ---------------------------------------------------------------------------
// Main MFMA kernel: BT=32, 512 threads, 1 block/CU
// ---------------------------------------------------------------------------
extern "C" __global__ __launch_bounds__(512, 2)
void rnn_wavefn_mfma_kernel(const float* __restrict__ inputs,
                            const float* __restrict__ Wih0,
                            const float* __restrict__ bih0,
                            const float* __restrict__ bhh0,
                            const float* __restrict__ bih1,
                            const float* __restrict__ bhh1,
                            const float* __restrict__ b1,
                            const float* __restrict__ W2,
                            const float* __restrict__ b2,
                            const _Float16* __restrict__ Whh0_1,
                            const _Float16* __restrict__ Whh0_2,
                            const _Float16* __restrict__ Wih1_1,
                            const _Float16* __restrict__ Wih1_2,
                            const _Float16* __restrict__ Whh1_1,
                            const _Float16* __restrict__ Whh1_2,
                            const _Float16* __restrict__ W1_1,
                            const _Float16* __restrict__ W1_2,
                            float* __restrict__ out) {
  // S0: GRU0 gates (cols 0..383). cos-frag arrays alias its first 16 KB
  // (live ranges disjoint: S0 live GEMM->C0; cs live C1->HDN).
  __shared__ __align__(16) float S0[BTM][S0P];   // 49,280 B
  __shared__ float S1[BTM][S1P];                 // 65,664 B  r,z|gh_n|gi_n/hdn
  __shared__ _Float16 h1A1[4096], h1A2[4096];    // A-frag split layouts
  __shared__ _Float16 h2A1[4096], h2A2[4096];    // 4 x 8 KB = 32,768 B
  __shared__ float xin[BTM][2];
  __shared__ uint32_t skey[NSTEPS][2];           // per-step threefry keys, 1 KB

  _Float16* const csA1 = (_Float16*)&S0[0][0];
  _Float16* const csA2 = csA1 + 4096;

  const int tid = threadIdx.x;
  const int b0 = blockIdx.x * BTM;
  const int wv = tid >> 6;        // 0..7
  const int lane = tid & 63;
  const int lm = lane & 15;
  const int m0 = (lane >> 4) * 4;

  // combine ownership: b = tid&31, d in [8*(tid>>5), +8)
  const int cb = tid & 31;
  const int ct5 = tid >> 5;       // 0..15
  const int d0 = ct5 * 8;
  // A-frag base for this thread's (cb, d-octet): contiguous half8
  const int ibase = ((cb >> 4) * 2048 +
                     (((ct5 >> 2) << 6) + ((ct5 & 3) << 4) + (cb & 15)) * 8);

  float h1r[8], h2r[8];
#pragma unroll
  for (int i = 0; i < 8; ++i) { h1r[i] = 0.0f; h2r[i] = 0.0f; }
  for (int i = tid; i < 4096; i += THM) {
    h1A1[i] = (_Float16)0.0f; h1A2[i] = (_Float16)0.0f;
    h2A1[i] = (_Float16)0.0f; h2A2[i] = (_Float16)0.0f;
  }
  if (tid < BTM * 2) {
    xin[tid >> 1][tid & 1] = inputs[(b0 + (tid >> 1)) * 2 + (tid & 1)];
  }
  if (tid < NSTEPS) {   // key schedule depends only on n: integer, bit-exact
    uint32_t a, bk;
    tf2x32(0u, 42u, 0u, (uint32_t)tid, a, bk);
    skey[tid][0] = a;
    skey[tid][1] = bk;
  }
  __syncthreads();

  // OUT for step np: dots over hdn (S1 cols 384..511) + softmax + sample.
  // Runs inside the merged GEMM phase of step np+1 (disjoint LDS regions).
  auto do_out = [&](int np) {
    const float* __restrict__ W2p = W2 + (size_t)np * 2 * HDIM;
    const float* __restrict__ b2p = b2 + (size_t)np * 2;
    const int ln = tid & 15;
    const int ob = tid >> 4;    // 0..31
    const int kb = ln * 8;
    float a0 = 0.0f, a1 = 0.0f;
#pragma unroll
    for (int k = 0; k < 8; ++k) {
      const float hd = S1[ob][384 + kb + k];
      a0 = fmaf(W2p[kb + k], hd, a0);
      a1 = fmaf(W2p[HDIM + kb + k], hd, a1);
    }
#pragma unroll
    for (int off = 8; off >= 1; off >>= 1) {
      a0 += __shfl_xor(a0, off, 16);
      a1 += __shfl_xor(a1, off, 16);
    }
    if (ln < 2) {
      // both lanes compute identical p0,p1 (same op sequence -> bit-exact);
      // ln==0 owns u0/z0, ln==1 owns u1/z1, compare via shfl (bit-exact).
      const float l0 = a0 + b2p[0];
      const float l1 = a1 + b2p[1];
      const float m = fmaxf(l0, l1);
      const float e0 = expf(l0 - m);
      const float e1 = expf(l1 - m);
      const float sum = e0 + e1;
      const float p0 = e0 / sum + 1e-10f;
      const float p1 = e1 / sum + 1e-10f;
      const int gb = b0 + ob;
      uint32_t o0, o1;
      tf2x32(skey[np][0], skey[np][1], 0u, (uint32_t)(2 * gb + ln), o0, o1);
      const float u = u01_from_bits(o0 ^ o1);
      const float g = -logf(-logf(u));
      const float zv = logf((ln == 0) ? p0 : p1) + g;
      const float zo = __shfl_xor(zv, 1, 16);
      if (ln == 0) {
        out[((size_t)gb * NSTEPS + np) * 2 + 0] = p0;
        out[((size_t)gb * NSTEPS + np) * 2 + 1] = p1;
        const int smp = (zo > zv) ? 1 : 0;   // zo = z1, zv = z0
        xin[ob][0] = (smp == 0) ? 1.0f : 0.0f;
        xin[ob][1] = (smp == 1) ? 1.0f : 0.0f;
      }
    }
  };

  // B double-buffer lives across phases; [0] is prefetched cross-barrier.
  half8 Bb1[2][4], Bb2[2][4];
  load_B(Whh0_1, Whh0_2, wv * 3, lane, Bb1[0], Bb2[0]);   // prologue n=0

  for (int n = 0; n < NSTEPS; ++n) {
    const float* __restrict__ Wih0n = Wih0 + (size_t)n * G3H * 2;
    const float* __restrict__ bih0n = bih0 + (size_t)n * G3H;
    const float* __restrict__ bhh0n = bhh0 + (size_t)n * G3H;
    const float* __restrict__ bih1n = bih1 + (size_t)n * G3H;
    const float* __restrict__ bhh1n = bhh1 + (size_t)n * G3H;
    const float* __restrict__ b1n = b1 + (size_t)n * HDIM;
    const size_t fo3 = (size_t)n * 49152;
    const size_t fo1 = (size_t)n * 16384;

    // ---------- merged GEMM: GH0 (h1 x Whh0 -> S0) + GH1a (h2 x Whh1 -> S1)
    // + OUT(n-1) (reads S1 cols 384..511; GEMM writes S0 + S1 cols 0..383).
    {
      half8 A1[2][4], A2[2][4];
      load_Afrag(h1A1, lane, A1);
      load_Afrag(h1A2, lane, A2);
      float bv[6];
#pragma unroll
      for (int t = 0; t < 6; ++t)
        bv[t] = ((t < 3) ? bhh0n : bhh1n)[(wv * 3 + (t % 3)) * 16 + lm];
#pragma unroll
      for (int t = 0; t < 6; ++t) {
        const int cur = t & 1;
        if (t < 5) {
          const int tn = t + 1;
          const _Float16* nB1 = (tn < 3) ? (Whh0_1 + fo3) : (Whh1_1 + fo3);
          const _Float16* nB2 = (tn < 3) ? (Whh0_2 + fo3) : (Whh1_2 + fo3);
          load_B(nB1, nB2, wv * 3 + (tn % 3), lane, Bb1[cur ^ 1], Bb2[cur ^ 1]);
        }
        if (t == 3) {   // switch A to h2 for GH1a jobs
          load_Afrag(h2A1, lane, A1);
          load_Afrag(h2A2, lane, A2);
        }
        const int jt = wv * 3 + (t % 3);
        f32x4 c1[2] = {{0.f,0.f,0.f,0.f},{0.f,0.f,0.f,0.f}};
        f32x4 c2[2] = {{0.f,0.f,0.f,0.f},{0.f,0.f,0.f,0.f}};
        mfma_regs(A1, A2, Bb1[cur], Bb2[cur], c1, c2);
        const int col = jt * 16 + lm;
        if (t < 3) {
#pragma unroll
          for (int mt = 0; mt < 2; ++mt)
#pragma unroll
            for (int r = 0; r < 4; ++r)
              S0[mt * 16 + m0 + r][col] = bv[t] + fmaf(c2[mt][r], LO_INV, c1[mt][r]);
        } else {
#pragma unroll
          for (int mt = 0; mt < 2; ++mt)
#pragma unroll
            for (int r = 0; r < 4; ++r)
              S1[mt * 16 + m0 + r][col] = bv[t] + fmaf(c2[mt][r], LO_INV, c1[mt][r]);
        }
      }
    }
    if (n > 0) do_out(n - 1);   // hides under the B-stream stalls above
    __syncthreads();

    // ---------- C0: GRU0 combine -> h1 regs + one b128 A-frag write per array
    {
      // cross-barrier prefetch: GH1b tile0 (latency hidden under combine VALU)
      load_B(Wih1_1 + fo3, Wih1_2 + fo3, wv * 3, lane, Bb1[0], Bb2[0]);
      const float x0 = xin[cb][0];
      const float x1 = xin[cb][1];
      float wr[16], wz[16], wn[16], br[8], bz[8], bn[8];
#pragma unroll
      for (int q = 0; q < 4; ++q) {
        *(float4*)&wr[q * 4] = *(const float4*)(Wih0n + d0 * 2 + q * 4);
        *(float4*)&wz[q * 4] = *(const float4*)(Wih0n + (d0 + 128) * 2 + q * 4);
        *(float4*)&wn[q * 4] = *(const float4*)(Wih0n + (d0 + 256) * 2 + q * 4);
      }
      *(float4*)&br[0] = *(const float4*)(bih0n + d0);
      *(float4*)&br[4] = *(const float4*)(bih0n + d0 + 4);
      *(float4*)&bz[0] = *(const float4*)(bih0n + 128 + d0);
      *(float4*)&bz[4] = *(const float4*)(bih0n + 128 + d0 + 4);
      *(float4*)&bn[0] = *(const float4*)(bih0n + 256 + d0);
      *(float4*)&bn[4] = *(const float4*)(bih0n + 256 + d0 + 4);
      half8 o1, o2;
#pragma unroll
      for (int j = 0; j < 8; ++j) {
        const int d = d0 + j;
        const float gir = fmaf(wr[2 * j], x0, fmaf(wr[2 * j + 1], x1, br[j]));
        const float giz = fmaf(wz[2 * j], x0, fmaf(wz[2 * j + 1], x1, bz[j]));
        const float gin = fmaf(wn[2 * j], x0, fmaf(wn[2 * j + 1], x1, bn[j]));
        const float r = sigmoidf(gir + S0[cb][d]);
        const float z = sigmoidf(giz + S0[cb][d + 128]);
        const float nn = ftanhf(gin + r * S0[cb][d + 256]);
        const float h1n = (1.0f - z) * nn + z * h1r[j];
        h1r[j] = h1n;
        _Float16 a1, a2s;
        split_f16(h1n, a1, a2s);
        o1[j] = a1;
        o2[j] = a2s;
      }
      *(half8*)(h1A1 + ibase) = o1;
      *(half8*)(h1A2 + ibase) = o2;
    }
    __syncthreads();

    // ---------- GH1b: gi1 = bih1 + Wih1 . h1new; r,z += into S1; gi_n separate
    {
      half8 A1[2][4], A2[2][4];
      load_Afrag(h1A1, lane, A1);
      load_Afrag(h1A2, lane, A2);
      float bv[3];
#pragma unroll
      for (int t = 0; t < 3; ++t) bv[t] = bih1n[(wv * 3 + t) * 16 + lm];
#pragma unroll
      for (int t = 0; t < 3; ++t) {
        const int cur = t & 1;
        if (t < 2)
          load_B(Wih1_1 + fo3, Wih1_2 + fo3, wv * 3 + t + 1, lane,
                 Bb1[cur ^ 1], Bb2[cur ^ 1]);
        const int jt = wv * 3 + t;
        f32x4 c1[2] = {{0.f,0.f,0.f,0.f},{0.f,0.f,0.f,0.f}};
        f32x4 c2[2] = {{0.f,0.f,0.f,0.f},{0.f,0.f,0.f,0.f}};
        mfma_regs(A1, A2, Bb1[cur], Bb2[cur], c1, c2);
        const int col = jt * 16 + lm;
        if (jt < 16) {   // r,z: accumulate gi+gh (same-thread slots as GH1a)
#pragma unroll
          for (int mt = 0; mt < 2; ++mt)
#pragma unroll
            for (int r = 0; r < 4; ++r)
              S1[mt * 16 + m0 + r][col] += bv[t] + fmaf(c2[mt][r], LO_INV, c1[mt][r]);
        } else {         // gi_n at col+128 (cols 384..511)
#pragma unroll
          for (int mt = 0; mt < 2; ++mt)
#pragma unroll
            for (int r = 0; r < 4; ++r)
              S1[mt * 16 + m0 + r][col + 128] = bv[t] + fmaf(c2[mt][r], LO_INV, c1[mt][r]);
        }
      }
    }
    __syncthreads();

    // ---------- C1: GRU1 combine -> h2 regs; h2/cos frag b128 writes
    half8 hb1[4], hb2[4];   // HDN W1 prefetch (used after next barrier)
    {
      load_B(W1_1 + fo1, W1_2 + fo1, wv, lane, hb1, hb2);
      // next-step merged tile0 prefetch (Whh0 of n+1)
      const size_t fo3n = (size_t)((n + 1 < NSTEPS) ? n + 1 : n) * 49152;
      load_B(Whh0_1 + fo3n, Whh0_2 + fo3n, wv * 3, lane, Bb1[0], Bb2[0]);
      half8 o1, o2, p1, p2;
#pragma unroll
      for (int j = 0; j < 8; ++j) {
        const int d = d0 + j;
        const float r = sigmoidf(S1[cb][d]);
        const float z = sigmoidf(S1[cb][d + 128]);
        const float nn = ftanhf(S1[cb][d + 384] + r * S1[cb][d + 256]);
        const float h2n = (1.0f - z) * nn + z * h2r[j];
        h2r[j] = h2n;
        _Float16 a1, a2s;
        split_f16(h2n, a1, a2s);
        o1[j] = a1;
        o2[j] = a2s;
        const float cv = fcosx(h2n) + 1e-10f;   // |h2n| <= 1: v_cos valid
        split_f16(cv, a1, a2s);
        p1[j] = a1;
        p2[j] = a2s;
      }
      *(half8*)(h2A1 + ibase) = o1;
      *(half8*)(h2A2 + ibase) = o2;
      *(half8*)(csA1 + ibase) = p1;
      *(half8*)(csA2 + ibase) = p2;
    }
    __syncthreads();

    // ---------- HDN: S1[b][384+d] = relu(b1[d] + W1[d,:].cos[b,:])
    {
      const float bias = b1n[wv * 16 + lm];
      half8 A1[2][4], A2[2][4];
      load_Afrag(csA1, lane, A1);
      load_Afrag(csA2, lane, A2);
      f32x4 c1[2] = {{0.f,0.f,0.f,0.f},{0.f,0.f,0.f,0.f}};
      f32x4 c2[2] = {{0.f,0.f,0.f,0.f},{0.f,0.f,0.f,0.f}};
      mfma_regs(A1, A2, hb1, hb2, c1, c2);
      const int col = wv * 16 + lm;
#pragma unroll
      for (int mt = 0; mt < 2; ++mt)
#pragma unroll
        for (int r = 0; r < 4; ++r)
          S1[mt * 16 + m0 + r][384 + col] =
              fmaxf(bias + fmaf(c2[mt][r], LO_INV, c1[mt][r]), 0.0f);
    }
    __syncthreads();
  }

  // epilogue: OUT for the final step
  do_out(NSTEPS - 1);
}

// ---------------------------------------------------------------------------
// Fallback: R3 fp32-VALU kernel (proven, 7.2 ms) — used if ws too small.
// ---------------------------------------------------------------------------
extern "C" __global__ __launch_bounds__(256, 2)
void rnn_wavefn_fp32_kernel(const float* __restrict__ inputs,
                            const float* __restrict__ Wih0,
                            const float* __restrict__ Whh0,
                            const float* __restrict__ bih0,
                            const float* __restrict__ bhh0,
                            const float* __restrict__ Wih1,
                            const float* __restrict__ Whh1,
                            const float* __restrict__ bih1,
                            const float* __restrict__ bhh1,
                            const float* __restrict__ W1,
                            const float* __restrict__ b1,
                            const float* __restrict__ W2,
                            const float* __restrict__ b2,
                            float* __restrict__ out) {
  __shared__ float h1[BT][HP];
  __shared__ float h2[BT][HP];
  __shared__ float S[BT][SP];
  __shared__ float xin[BT][2];

  const int tid = threadIdx.x;
  const int b0 = blockIdx.x * BT;
  const int tj = tid >> 2;
  const int tq = tid & 3;

  for (int i = tid; i < BT * HP; i += THREADS) {
    ((float*)h1)[i] = 0.0f;
    ((float*)h2)[i] = 0.0f;
  }
  if (tid < BT * 2) {
    xin[tid >> 1][tid & 1] = inputs[(b0 + (tid >> 1)) * 2 + (tid & 1)];
  }
  __syncthreads();

  for (int n = 0; n < NSTEPS; ++n) {
    const float* __restrict__ Wih0n = Wih0 + (size_t)n * G3H * 2;
    const float* __restrict__ Whh0n = Whh0 + (size_t)n * G3H * HDIM;
    const float* __restrict__ bih0n = bih0 + (size_t)n * G3H;
    const float* __restrict__ bhh0n = bhh0 + (size_t)n * G3H;
    const float* __restrict__ Wih1n = Wih1 + (size_t)n * G3H * HDIM;
    const float* __restrict__ Whh1n = Whh1 + (size_t)n * G3H * HDIM;
    const float* __restrict__ bih1n = bih1 + (size_t)n * G3H;
    const float* __restrict__ bhh1n = bhh1 + (size_t)n * G3H;
    const float* __restrict__ W1n = W1 + (size_t)n * HDIM * HDIM;
    const float* __restrict__ b1n = b1 + (size_t)n * HDIM;
    const float* __restrict__ W2n = W2 + (size_t)n * 2 * HDIM;
    const float* __restrict__ b2n = b2 + (size_t)n * 2;

    {
      float acc[6][4];
#pragma unroll
      for (int g = 0; g < 6; ++g) {
        const float bias = bhh0n[tj + g * 64];
#pragma unroll
        for (int i = 0; i < 4; ++i) acc[g][i] = bias;
      }
      for (int kk = 0; kk < HDIM; kk += 16) {
#pragma unroll
        for (int s = 0; s < 4; ++s) {
          const int k = kk + s * 4;
          float4 w[6];
#pragma unroll
          for (int g = 0; g < 6; ++g)
            w[g] = *(const float4*)(Whh0n + (size_t)(tj + g * 64) * HDIM + k);
#pragma unroll
          for (int i = 0; i < 4; ++i) {
            const float4 hv = *(const float4*)&h1[tq + 4 * i][k];
#pragma unroll
            for (int g = 0; g < 6; ++g) acc[g][i] = dot4(w[g], hv, acc[g][i]);
          }
        }
      }
#pragma unroll
      for (int g = 0; g < 6; ++g)
#pragma unroll
        for (int i = 0; i < 4; ++i) S[tq + 4 * i][tj + g * 64] = acc[g][i];
    }
    __syncthreads();

#pragma unroll
    for (int rep = 0; rep < (BT * HDIM) / THREADS; ++rep) {
      const int idx = tid + rep * THREADS;
      const int b = idx >> 7;
      const int d = idx & 127;
      const float x0 = xin[b][0];
      const float x1 = xin[b][1];
      const float gir = fmaf(Wih0n[d * 2 + 0], x0, fmaf(Wih0n[d * 2 + 1], x1, bih0n[d]));
      const float giz = fmaf(Wih0n[(d + 128) * 2 + 0], x0,
                             fmaf(Wih0n[(d + 128) * 2 + 1], x1, bih0n[d + 128]));
      const float gin = fmaf(Wih0n[(d + 256) * 2 + 0], x0,
                             fmaf(Wih0n[(d + 256) * 2 + 1], x1, bih0n[d + 256]));
      const float r = sigmoidf(gir + S[b][d]);
      const float z = sigmoidf(giz + S[b][d + 128]);
      const float nn = tanhf(gin + r * S[b][d + 256]);
      h1[b][d] = (1.0f - z) * nn + z * h1[b][d];
    }
    __syncthreads();

    {
      float acc[6][4];
#pragma unroll
      for (int g = 0; g < 6; ++g) {
        const float bias = bhh1n[tj + g * 64];
#pragma unroll
        for (int i = 0; i < 4; ++i) acc[g][i] = bias;
      }
      for (int kk = 0; kk < HDIM; kk += 16) {
#pragma unroll
        for (int s = 0; s < 4; ++s) {
          const int k = kk + s * 4;
          float4 w[6];
#pragma unroll
          for (int g = 0; g < 6; ++g)
            w[g] = *(const float4*)(Whh1n + (size_t)(tj + g * 64) * HDIM + k);
#pragma unroll
          for (int i = 0; i < 4; ++i) {
            const float4 hv = *(const float4*)&h2[tq + 4 * i][k];
#pragma unroll
            for (int g = 0; g < 6; ++g) acc[g][i] = dot4(w[g], hv, acc[g][i]);
          }
        }
      }
#pragma unroll
      for (int g = 0; g < 6; ++g)
#pragma unroll
        for (int i = 0; i < 4; ++i) S[tq + 4 * i][tj + g * 64] = acc[g][i];
    }

    {
      float acc[6][4];
#pragma unroll
      for (int g = 0; g < 6; ++g) {
        const float bias = bih1n[tj + g * 64];
#pragma unroll
        for (int i = 0; i < 4; ++i) acc[g][i] = bias;
      }
      for (int kk = 0; kk < HDIM; kk += 16) {
#pragma unroll
        for (int s = 0; s < 4; ++s) {
          const int k = kk + s * 4;
          float4 w[6];
#pragma unroll
          for (int g = 0; g < 6; ++g)
            w[g] = *(const float4*)(Wih1n + (size_t)(tj + g * 64) * HDIM + k);
#pragma unroll
          for (int i = 0; i < 4; ++i) {
            const float4 hv = *(const float4*)&h1[tq + 4 * i][k];
#pragma unroll
            for (int g = 0; g < 6; ++g) acc[g][i] = dot4(w[g], hv, acc[g][i]);
          }
        }
      }
#pragma unroll
      for (int g = 0; g < 6; ++g) {
        const int row = tj + g * 64;
#pragma unroll
        for (int i = 0; i < 4; ++i) {
          if (row < 256) S[tq + 4 * i][row] += acc[g][i];
          else           S[tq + 4 * i][row + 128] = acc[g][i];
        }
      }
    }
    __syncthreads();

#pragma unroll
    for (int rep = 0; rep < (BT * HDIM) / THREADS; ++rep) {
      const int idx = tid + rep * THREADS;
      const int b = idx >> 7;
      const int d = idx & 127;
      const float r = sigmoidf(S[b][d]);
      const float z = sigmoidf(S[b][d + 128]);
      const float nn = tanhf(S[b][d + 384] + r * S[b][d + 256]);
      const float h2n = (1.0f - z) * nn + z * h2[b][d];
      h2[b][d] = h2n;
      S[b][d] = cosf(h2n) + 1e-10f;
    }
    __syncthreads();

    {
      float acc[2][4];
#pragma unroll
      for (int g = 0; g < 2; ++g) {
        const float bias = b1n[tj + g * 64];
#pragma unroll
        for (int i = 0; i < 4; ++i) acc[g][i] = bias;
      }
      for (int kk = 0; kk < HDIM; kk += 16) {
#pragma unroll
        for (int s = 0; s < 4; ++s) {
          const int k = kk + s * 4;
          float4 w[2];
          w[0] = *(const float4*)(W1n + (size_t)(tj)*HDIM + k);
          w[1] = *(const float4*)(W1n + (size_t)(tj + 64) * HDIM + k);
#pragma unroll
          for (int i = 0; i < 4; ++i) {
            const float4 sv = *(const float4*)&S[tq + 4 * i][k];
            acc[0][i] = dot4(w[0], sv, acc[0][i]);
            acc[1][i] = dot4(w[1], sv, acc[1][i]);
          }
        }
      }
#pragma unroll
      for (int g = 0; g < 2; ++g)
#pragma unroll
        for (int i = 0; i < 4; ++i)
          S[tq + 4 * i][384 + tj + g * 64] = fmaxf(acc[g][i], 0.0f);
    }
    __syncthreads();

    {
      const int ln = tid & 15;
      const int b = tid >> 4;
      const int kb = ln * 8;
      float a0 = 0.0f, a1 = 0.0f;
#pragma unroll
      for (int k = 0; k < 8; ++k) {
        const float hd = S[b][384 + kb + k];
        a0 = fmaf(W2n[kb + k], hd, a0);
        a1 = fmaf(W2n[HDIM + kb + k], hd, a1);
      }
#pragma unroll
      for (int off = 8; off >= 1; off >>= 1) {
        a0 += __shfl_xor(a0, off, 16);
        a1 += __shfl_xor(a1, off, 16);
      }
      if (ln == 0) {
        const float l0 = a0 + b2n[0];
        const float l1 = a1 + b2n[1];
        const float m = fmaxf(l0, l1);
        const float e0 = expf(l0 - m);
        const float e1 = expf(l1 - m);
        const float sum = e0 + e1;
        const float p0 = e0 / sum + 1e-10f;
        const float p1 = e1 / sum + 1e-10f;
        const int gb = b0 + b;
        out[((size_t)gb * NSTEPS + n) * 2 + 0] = p0;
        out[((size_t)gb * NSTEPS + n) * 2 + 1] = p1;

        uint32_t k0n, k1n;
        tf2x32(0u, 42u, 0u, (uint32_t)n, k0n, k1n);
        uint32_t o0, o1;
        tf2x32(k0n, k1n, 0u, (uint32_t)(2 * gb), o0, o1);
        const float u0 = u01_from_bits(o0 ^ o1);
        tf2x32(k0n, k1n, 0u, (uint32_t)(2 * gb + 1), o0, o1);
        const float u1 = u01_from_bits(o0 ^ o1);
        const float g0 = -logf(-logf(u0));
        const float g1 = -logf(-logf(u1));
        const float z0 = logf(p0) + g0;
        const float z1 = logf(p1) + g1;
        const int smp = (z1 > z0) ? 1 : 0;
        xin[b][0] = (smp == 0) ? 1.0f : 0.0f;
        xin[b][1] = (smp == 1) ? 1.0f : 0.0f;
      }
    }
    __syncthreads();
  }
}

extern "C" void kernel_launch(void* const* d_in, const int* in_sizes, int n_in,
                              void* d_out, int out_size, void* d_ws, size_t ws_size,
                              hipStream_t stream) {
  (void)in_sizes; (void)n_in; (void)out_size;
  const float* inputs = (const float*)d_in[0];
  const float* Wih0 = (const float*)d_in[1];
  const float* Whh0 = (const float*)d_in[2];
  const float* bih0 = (const float*)d_in[3];
  const float* bhh0 = (const float*)d_in[4];
  const float* Wih1 = (const float*)d_in[5];
  const float* Whh1 = (const float*)d_in[6];
  const float* bih1 = (const float*)d_in[7];
  const float* bhh1 = (const float*)d_in[8];
  const float* W1 = (const float*)d_in[9];
  const float* b1 = (const float*)d_in[10];
  const float* W2 = (const float*)d_in[11];
  const float* b2 = (const float*)d_in[12];
  float* out = (float*)d_out;

  constexpr size_t EB = 6291456;        // 128*24*4*64*8
  constexpr size_t EW1 = 2097152;       // 128*8*4*64*8
  constexpr size_t WS_NEEDED = (6 * EB + 2 * EW1) * sizeof(_Float16);

  if (ws_size >= WS_NEEDED) {
    _Float16* w = (_Float16*)d_ws;
    _Float16* Whh0_1 = w;
    _Float16* Whh0_2 = w + EB;
    _Float16* Wih1_1 = w + 2 * EB;
    _Float16* Wih1_2 = w + 3 * EB;
    _Float16* Whh1_1 = w + 4 * EB;
    _Float16* Whh1_2 = w + 5 * EB;
    _Float16* W1_1 = w + 6 * EB;
    _Float16* W1_2 = w + 6 * EB + EW1;

    hipLaunchKernelGGL(preprocess_split_kernel, dim3(3072), dim3(256), 0, stream,
                       Whh0, Whh0_1, Whh0_2, 786432, 24);
    hipLaunchKernelGGL(preprocess_split_kernel, dim3(3072), dim3(256), 0, stream,
                       Wih1, Wih1_1, Wih1_2, 786432, 24);
    hipLaunchKernelGGL(preprocess_split_kernel, dim3(3072), dim3(256), 0, stream,
                       Whh1, Whh1_1, Whh1_2, 786432, 24);
    hipLaunchKernelGGL(preprocess_split_kernel, dim3(1024), dim3(256), 0, stream,
                       W1, W1_1, W1_2, 262144, 8);
    hipLaunchKernelGGL(rnn_wavefn_mfma_kernel, dim3(8192 / BTM), dim3(THM), 0, stream,
                       inputs, Wih0, bih0, bhh0, bih1, bhh1, b1, W2, b2,
                       Whh0_1, Whh0_2, Wih1_1, Wih1_2, Whh1_1, Whh1_2, W1_1, W1_2,
                       out);
  } else {
    hipLaunchKernelGGL(rnn_wavefn_fp32_kernel, dim3(8192 / BT), dim3(THREADS), 0, stream,
                       inputs, Wih0, Whh0, bih0, bhh0, Wih1, Whh1, bih1, bhh1,
                       W1, b1, W2, b2, out);
  }
}